// Round 4
// baseline (68.680 us; speedup 1.0000x reference)
//
#include <hip/hip_runtime.h>

#define NGRID 64
#define NEL (NGRID*NGRID*NGRID)   /* 262144 */
#define PADMAX (NEL + 256*64)     /* 278528: worst-case 64-padded bucket total */
#define IDX(i,j,k) ((((i)*64 + (j)) * 64) + (k))

// ---- workspace layout (bytes) ----
#define WS_U4     0                          // NEL float4      = 4 MB
#define WS_C      (WS_U4 + NEL*16)           // 8*NEL float4    = 32 MB
#define WS_SORTED (WS_C + 8*NEL*16)          // PADMAX i32
#define WS_TYPES  (WS_SORTED + PADMAX*4)     // NEL u8
#define WS_BHIST  (WS_TYPES + NEL)           // 256*256 i32 (hist[t*256+b])
#define WS_BINTOT (WS_BHIST + 256*256*4)     // 256 i32
#define WS_NEEDED (size_t)(WS_BINTOT + 256*4)

__device__ __forceinline__ int type_of(const float* __restrict__ rho, int i, int j, int k) {
    int i1 = (i + 1) & 63, j1 = (j + 1) & 63, k1 = (k + 1) & 63;
    // typeFilter[di][dj][dk] = 2^(di*4 + dj*2 + dk); OFFSETS order -> bits {0,4,2,6,1,5,3,7}
    int t = 0;
    t |= (rho[IDX(i,  j,  k )] > 0.5f ? 1 : 0) << 0;
    t |= (rho[IDX(i1, j,  k )] > 0.5f ? 1 : 0) << 4;
    t |= (rho[IDX(i,  j1, k )] > 0.5f ? 1 : 0) << 2;
    t |= (rho[IDX(i1, j1, k )] > 0.5f ? 1 : 0) << 6;
    t |= (rho[IDX(i,  j,  k1)] > 0.5f ? 1 : 0) << 1;
    t |= (rho[IDX(i1, j,  k1)] > 0.5f ? 1 : 0) << 5;
    t |= (rho[IDX(i,  j1, k1)] > 0.5f ? 1 : 0) << 3;
    t |= (rho[IDX(i1, j1, k1)] > 0.5f ? 1 : 0) << 7;
    return t;
}

// K1: pack U->float4, compute types, per-block histogram. 256 blocks x 1024 thr.
__global__ __launch_bounds__(1024) void k1_pack_types_hist(
    const float* __restrict__ U, const float* __restrict__ rho,
    float4* __restrict__ U4, unsigned char* __restrict__ types, int* __restrict__ bhist)
{
    __shared__ int lh[256];
    int tid = threadIdx.x;
    if (tid < 256) lh[tid] = 0;
    __syncthreads();
    int e = blockIdx.x * 1024 + tid;
    U4[e] = make_float4(U[3*e + 0], U[3*e + 1], U[3*e + 2], 0.0f);
    int k = e & 63, j = (e >> 6) & 63, i = (e >> 12) & 63;
    int t = type_of(rho, i, j, k);
    types[e] = (unsigned char)t;
    atomicAdd(&lh[t], 1);
    __syncthreads();
    if (tid < 256) bhist[tid * 256 + blockIdx.x] = lh[tid];
}

// K2: per type T, exclusive-scan hist over blocks; totals; init sorted[]=-1.
__global__ __launch_bounds__(256) void k2_scan_init(
    int* __restrict__ bhist, int* __restrict__ bintot, int* __restrict__ sorted)
{
    int gid = blockIdx.x * 256 + threadIdx.x;
    for (int p = gid; p < PADMAX; p += 256 * 256) sorted[p] = -1;

    __shared__ int s[256];
    int T = blockIdx.x, tid = threadIdx.x;
    int v = bhist[T * 256 + tid];
    s[tid] = v;
    __syncthreads();
    #pragma unroll
    for (int off = 1; off < 256; off <<= 1) {
        int tmp = (tid >= off) ? s[tid - off] : 0;
        __syncthreads();
        s[tid] += tmp;
        __syncthreads();
    }
    bhist[T * 256 + tid] = s[tid] - v;     // exclusive over blocks, within type
    if (tid == 255) bintot[T] = s[255];
}

// K3: scatter (t<<18)|e into 64-padded type-grouped order.
__global__ __launch_bounds__(1024) void k3_scatter(
    const unsigned char* __restrict__ types, const int* __restrict__ bhist,
    const int* __restrict__ bintot, int* __restrict__ sorted)
{
    __shared__ int lh[256];
    __shared__ int base[256];
    int tid = threadIdx.x;
    if (tid < 256) {
        lh[tid] = 0;
        base[tid] = (bintot[tid] + 63) & ~63;   // padded bucket size
    }
    __syncthreads();
    #pragma unroll
    for (int off = 1; off < 256; off <<= 1) {
        int tmp = 0;
        if (tid < 256 && tid >= off) tmp = base[tid - off];
        __syncthreads();
        if (tid < 256) base[tid] += tmp;        // inclusive scan of padded sizes
        __syncthreads();
    }
    int e = blockIdx.x * 1024 + tid;
    int t = types[e];
    int lrank = atomicAdd(&lh[t], 1);
    int padt = (bintot[t] + 63) & ~63;
    int pos = (base[t] - padt) + bhist[t * 256 + blockIdx.x] + lrank;
    sorted[pos] = (t << 18) | e;
}

// K4: per padded-sorted element. Wave-pure type (64-aligned buckets) ->
// readfirstlane makes the filter pointer scalar (s_load path, SGPR operands).
// Gather 8 float4 from U4, 24x24 matvec, scatter 8 float4 corner contributions.
__global__ __launch_bounds__(256) void k4_apply(
    const float4* __restrict__ U4, const float* __restrict__ filters,
    const int* __restrict__ sorted, float4* __restrict__ C)
{
    int p = blockIdx.x * 256 + threadIdx.x;
    int entry = sorted[p];
    int tw = __builtin_amdgcn_readfirstlane(entry);
    int t = (tw >> 18) & 255;                    // holes-only waves -> 255 (in bounds)
    const float* __restrict__ F = filters + t * 576;   // SGPR base -> s_load

    if (entry >= 0) {
        int e = entry & 0x3FFFF;
        int k = e & 63, j = (e >> 6) & 63, i = (e >> 12) & 63;
        int i1 = (i + 1) & 63, j1 = (j + 1) & 63, k1 = (k + 1) & 63;

        int nodes[8];
        nodes[0] = IDX(i,  j,  k );
        nodes[1] = IDX(i1, j,  k );
        nodes[2] = IDX(i,  j1, k );
        nodes[3] = IDX(i1, j1, k );
        nodes[4] = IDX(i,  j,  k1);
        nodes[5] = IDX(i1, j,  k1);
        nodes[6] = IDX(i,  j1, k1);
        nodes[7] = IDX(i1, j1, k1);

        float Ue[24];
        #pragma unroll
        for (int m = 0; m < 8; ++m) {
            float4 u = U4[nodes[m]];
            Ue[3*m + 0] = u.x;
            Ue[3*m + 1] = u.y;
            Ue[3*m + 2] = u.z;
        }

        float o[24];
        #pragma unroll
        for (int r = 0; r < 24; ++r) {
            float a = 0.0f;
            #pragma unroll
            for (int q = 0; q < 24; ++q)
                a = fmaf(F[r * 24 + q], Ue[q], a);   // SGPR filter operand
            o[r] = a;
        }

        #pragma unroll
        for (int c = 0; c < 8; ++c)
            C[c * NEL + nodes[c]] = make_float4(o[3*c + 0], o[3*c + 1], o[3*c + 2], 0.0f);
    }
}

// K5: per node, sum the 8 corner contribution arrays. Fully coalesced.
__global__ __launch_bounds__(256) void k5_reduce(
    const float4* __restrict__ C, float* __restrict__ out)
{
    int n = blockIdx.x * 256 + threadIdx.x;
    float a0 = 0.f, a1 = 0.f, a2 = 0.f;
    #pragma unroll
    for (int c = 0; c < 8; ++c) {
        float4 v = C[c * NEL + n];
        a0 += v.x; a1 += v.y; a2 += v.z;
    }
    out[n*3 + 0] = a0;
    out[n*3 + 1] = a1;
    out[n*3 + 2] = a2;
}

// Fallback (ws too small): round-1 atomic scatter kernel.
__global__ __launch_bounds__(256) void fe_apply_atomic(
    const float* __restrict__ U, const float* __restrict__ rho,
    const float* __restrict__ filters, float* __restrict__ out)
{
    int e = blockIdx.x * blockDim.x + threadIdx.x;
    int k = e & 63, j = (e >> 6) & 63, i = (e >> 12) & 63;
    int i1 = (i + 1) & 63, j1 = (j + 1) & 63, k1 = (k + 1) & 63;
    int nodes[8];
    nodes[0]=IDX(i,j,k);   nodes[1]=IDX(i1,j,k);   nodes[2]=IDX(i,j1,k);   nodes[3]=IDX(i1,j1,k);
    nodes[4]=IDX(i,j,k1);  nodes[5]=IDX(i1,j,k1);  nodes[6]=IDX(i,j1,k1);  nodes[7]=IDX(i1,j1,k1);
    int t = type_of(rho, i, j, k);
    float Ue[24];
    #pragma unroll
    for (int m = 0; m < 8; ++m) {
        int b = nodes[m] * 3;
        Ue[3*m+0]=U[b+0]; Ue[3*m+1]=U[b+1]; Ue[3*m+2]=U[b+2];
    }
    const float4* Kr = (const float4*)(filters + t * 576);
    #pragma unroll
    for (int r = 0; r < 24; ++r) {
        float a = 0.f;
        #pragma unroll
        for (int q = 0; q < 6; ++q) {
            float4 f = Kr[r*6+q];
            a = fmaf(f.x,Ue[4*q+0],a); a = fmaf(f.y,Ue[4*q+1],a);
            a = fmaf(f.z,Ue[4*q+2],a); a = fmaf(f.w,Ue[4*q+3],a);
        }
        atomicAdd(&out[nodes[r/3]*3 + (r%3)], a);
    }
}

extern "C" void kernel_launch(void* const* d_in, const int* in_sizes, int n_in,
                              void* d_out, int out_size, void* d_ws, size_t ws_size,
                              hipStream_t stream) {
    const float* U       = (const float*)d_in[0];
    const float* rho     = (const float*)d_in[1];
    const float* filters = (const float*)d_in[3];
    float* out = (float*)d_out;

    if (ws_size < WS_NEEDED) {
        hipMemsetAsync(out, 0, (size_t)out_size * sizeof(float), stream);
        fe_apply_atomic<<<dim3(NEL/256), dim3(256), 0, stream>>>(U, rho, filters, out);
        return;
    }

    char* ws = (char*)d_ws;
    float4*        U4     = (float4*)(ws + WS_U4);
    float4*        C      = (float4*)(ws + WS_C);
    int*           sorted = (int*)(ws + WS_SORTED);
    unsigned char* types  = (unsigned char*)(ws + WS_TYPES);
    int*           bhist  = (int*)(ws + WS_BHIST);
    int*           bintot = (int*)(ws + WS_BINTOT);

    k1_pack_types_hist<<<dim3(256),        dim3(1024), 0, stream>>>(U, rho, U4, types, bhist);
    k2_scan_init      <<<dim3(256),        dim3(256),  0, stream>>>(bhist, bintot, sorted);
    k3_scatter        <<<dim3(256),        dim3(1024), 0, stream>>>(types, bhist, bintot, sorted);
    k4_apply          <<<dim3(PADMAX/256), dim3(256),  0, stream>>>(U4, filters, sorted, C);
    k5_reduce         <<<dim3(NEL/256),    dim3(256),  0, stream>>>(C, out);
}

// Round 5
// 59.622 us; speedup vs baseline: 1.1519x; 1.1519x over previous
//
#include <hip/hip_runtime.h>

#define NGRID 64
#define NEL (NGRID*NGRID*NGRID)   /* 262144 */
#define PADMAX (NEL + 256*64)     /* 278528: worst-case 64-padded bucket total */
#define IDX(i,j,k) ((((i)*64 + (j)) * 64) + (k))

// ---- workspace layout (bytes) ----
// KUe32: 32 floats (128 B) per element, NATURAL element order.
// Corner c's 3-vector lives at float4 slot c (16c bytes). Two full cache
// lines per element, written entirely by one thread -> no write-allocate RMW.
#define WS_U4     0                          // NEL float4   = 4 MB
#define WS_KUE    (WS_U4 + NEL*16)           // NEL*128 B    = 33.5 MB
#define WS_SORTED (WS_KUE + (size_t)NEL*128) // PADMAX i32
#define WS_TYPES  (WS_SORTED + PADMAX*4)     // NEL u8
#define WS_BHIST  (WS_TYPES + NEL)           // 256*256 i32 (hist[t*256+b])
#define WS_BINTOT (WS_BHIST + 256*256*4)     // 256 i32
#define WS_NEEDED (size_t)(WS_BINTOT + 256*4)

__device__ __forceinline__ int type_of(const float* __restrict__ rho, int i, int j, int k) {
    int i1 = (i + 1) & 63, j1 = (j + 1) & 63, k1 = (k + 1) & 63;
    // typeFilter[di][dj][dk] = 2^(di*4 + dj*2 + dk); OFFSETS order -> bits {0,4,2,6,1,5,3,7}
    int t = 0;
    t |= (rho[IDX(i,  j,  k )] > 0.5f ? 1 : 0) << 0;
    t |= (rho[IDX(i1, j,  k )] > 0.5f ? 1 : 0) << 4;
    t |= (rho[IDX(i,  j1, k )] > 0.5f ? 1 : 0) << 2;
    t |= (rho[IDX(i1, j1, k )] > 0.5f ? 1 : 0) << 6;
    t |= (rho[IDX(i,  j,  k1)] > 0.5f ? 1 : 0) << 1;
    t |= (rho[IDX(i1, j,  k1)] > 0.5f ? 1 : 0) << 5;
    t |= (rho[IDX(i,  j1, k1)] > 0.5f ? 1 : 0) << 3;
    t |= (rho[IDX(i1, j1, k1)] > 0.5f ? 1 : 0) << 7;
    return t;
}

// K1: pack U->float4, compute types, per-block histogram. 256 blocks x 1024 thr.
__global__ __launch_bounds__(1024) void k1_pack_types_hist(
    const float* __restrict__ U, const float* __restrict__ rho,
    float4* __restrict__ U4, unsigned char* __restrict__ types, int* __restrict__ bhist)
{
    __shared__ int lh[256];
    int tid = threadIdx.x;
    if (tid < 256) lh[tid] = 0;
    __syncthreads();
    int e = blockIdx.x * 1024 + tid;
    U4[e] = make_float4(U[3*e + 0], U[3*e + 1], U[3*e + 2], 0.0f);
    int k = e & 63, j = (e >> 6) & 63, i = (e >> 12) & 63;
    int t = type_of(rho, i, j, k);
    types[e] = (unsigned char)t;
    atomicAdd(&lh[t], 1);
    __syncthreads();
    if (tid < 256) bhist[tid * 256 + blockIdx.x] = lh[tid];
}

// K2: per type T, exclusive-scan hist over blocks; totals; init sorted[]=-1.
__global__ __launch_bounds__(256) void k2_scan_init(
    int* __restrict__ bhist, int* __restrict__ bintot, int* __restrict__ sorted)
{
    int gid = blockIdx.x * 256 + threadIdx.x;
    for (int p = gid; p < PADMAX; p += 256 * 256) sorted[p] = -1;

    __shared__ int s[256];
    int T = blockIdx.x, tid = threadIdx.x;
    int v = bhist[T * 256 + tid];
    s[tid] = v;
    __syncthreads();
    #pragma unroll
    for (int off = 1; off < 256; off <<= 1) {
        int tmp = (tid >= off) ? s[tid - off] : 0;
        __syncthreads();
        s[tid] += tmp;
        __syncthreads();
    }
    bhist[T * 256 + tid] = s[tid] - v;     // exclusive over blocks, within type
    if (tid == 255) bintot[T] = s[255];
}

// K3: scatter (t<<18)|e into 64-padded type-grouped order.
__global__ __launch_bounds__(1024) void k3_scatter(
    const unsigned char* __restrict__ types, const int* __restrict__ bhist,
    const int* __restrict__ bintot, int* __restrict__ sorted)
{
    __shared__ int lh[256];
    __shared__ int base[256];
    int tid = threadIdx.x;
    if (tid < 256) {
        lh[tid] = 0;
        base[tid] = (bintot[tid] + 63) & ~63;   // padded bucket size
    }
    __syncthreads();
    #pragma unroll
    for (int off = 1; off < 256; off <<= 1) {
        int tmp = 0;
        if (tid < 256 && tid >= off) tmp = base[tid - off];
        __syncthreads();
        if (tid < 256) base[tid] += tmp;        // inclusive scan of padded sizes
        __syncthreads();
    }
    int e = blockIdx.x * 1024 + tid;
    int t = types[e];
    int lrank = atomicAdd(&lh[t], 1);
    int padt = (bintot[t] + 63) & ~63;
    int pos = (base[t] - padt) + bhist[t * 256 + blockIdx.x] + lrank;
    sorted[pos] = (t << 18) | e;
}

// K4: per padded-sorted element. Wave-pure type (64-aligned buckets) ->
// readfirstlane makes the filter pointer scalar (s_load path, SGPR operands).
// Gather 8 float4 from U4; 24x24 matvec; write 8 float4 (=2 full cache lines)
// contiguous at KUe32[e] in natural element order.
__global__ __launch_bounds__(256) void k4_apply(
    const float4* __restrict__ U4, const float* __restrict__ filters,
    const int* __restrict__ sorted, float4* __restrict__ KUe32)
{
    int p = blockIdx.x * 256 + threadIdx.x;
    int entry = sorted[p];
    int tw = __builtin_amdgcn_readfirstlane(entry);
    int t = (tw >> 18) & 255;                    // holes-only waves -> in-bounds dummy
    const float* __restrict__ F = filters + t * 576;   // SGPR base -> s_load

    if (entry >= 0) {
        int e = entry & 0x3FFFF;
        int k = e & 63, j = (e >> 6) & 63, i = (e >> 12) & 63;
        int i1 = (i + 1) & 63, j1 = (j + 1) & 63, k1 = (k + 1) & 63;

        int nodes[8];
        nodes[0] = IDX(i,  j,  k );
        nodes[1] = IDX(i1, j,  k );
        nodes[2] = IDX(i,  j1, k );
        nodes[3] = IDX(i1, j1, k );
        nodes[4] = IDX(i,  j,  k1);
        nodes[5] = IDX(i1, j,  k1);
        nodes[6] = IDX(i,  j1, k1);
        nodes[7] = IDX(i1, j1, k1);

        float Ue[24];
        #pragma unroll
        for (int m = 0; m < 8; ++m) {
            float4 u = U4[nodes[m]];
            Ue[3*m + 0] = u.x;
            Ue[3*m + 1] = u.y;
            Ue[3*m + 2] = u.z;
        }

        float o[24];
        #pragma unroll
        for (int r = 0; r < 24; ++r) {
            float a = 0.0f;
            #pragma unroll
            for (int q = 0; q < 24; ++q)
                a = fmaf(F[r * 24 + q], Ue[q], a);   // SGPR filter operand
            o[r] = a;
        }

        float4* __restrict__ dst = KUe32 + (size_t)e * 8;
        #pragma unroll
        for (int c = 0; c < 8; ++c)
            dst[c] = make_float4(o[3*c + 0], o[3*c + 1], o[3*c + 2], 0.0f);
    }
}

// K5: per node n, sum corner-slot float4 of the 8 incident elements.
// Natural-order KUe32 -> incident elements are spatial neighbors -> the two
// lines of each element get fully consumed by co-resident blocks (L2 reuse).
__global__ __launch_bounds__(256) void k5_reduce(
    const float4* __restrict__ KUe32, float* __restrict__ out)
{
    int n = blockIdx.x * 256 + threadIdx.x;
    int k = n & 63, j = (n >> 6) & 63, i = (n >> 12) & 63;

    const int DI[8] = {0,1,0,1,0,1,0,1};
    const int DJ[8] = {0,0,1,1,0,0,1,1};
    const int DK[8] = {0,0,0,0,1,1,1,1};

    float a0 = 0.f, a1 = 0.f, a2 = 0.f;
    #pragma unroll
    for (int c = 0; c < 8; ++c) {
        int ei = (i - DI[c]) & 63;
        int ej = (j - DJ[c]) & 63;
        int ek = (k - DK[c]) & 63;
        float4 v = KUe32[(size_t)IDX(ei, ej, ek) * 8 + c];
        a0 += v.x; a1 += v.y; a2 += v.z;
    }
    out[n*3 + 0] = a0;
    out[n*3 + 1] = a1;
    out[n*3 + 2] = a2;
}

// Fallback (ws too small): round-1 atomic scatter kernel.
__global__ __launch_bounds__(256) void fe_apply_atomic(
    const float* __restrict__ U, const float* __restrict__ rho,
    const float* __restrict__ filters, float* __restrict__ out)
{
    int e = blockIdx.x * blockDim.x + threadIdx.x;
    int k = e & 63, j = (e >> 6) & 63, i = (e >> 12) & 63;
    int i1 = (i + 1) & 63, j1 = (j + 1) & 63, k1 = (k + 1) & 63;
    int nodes[8];
    nodes[0]=IDX(i,j,k);   nodes[1]=IDX(i1,j,k);   nodes[2]=IDX(i,j1,k);   nodes[3]=IDX(i1,j1,k);
    nodes[4]=IDX(i,j,k1);  nodes[5]=IDX(i1,j,k1);  nodes[6]=IDX(i,j1,k1);  nodes[7]=IDX(i1,j1,k1);
    int t = type_of(rho, i, j, k);
    float Ue[24];
    #pragma unroll
    for (int m = 0; m < 8; ++m) {
        int b = nodes[m] * 3;
        Ue[3*m+0]=U[b+0]; Ue[3*m+1]=U[b+1]; Ue[3*m+2]=U[b+2];
    }
    const float4* Kr = (const float4*)(filters + t * 576);
    #pragma unroll
    for (int r = 0; r < 24; ++r) {
        float a = 0.f;
        #pragma unroll
        for (int q = 0; q < 6; ++q) {
            float4 f = Kr[r*6+q];
            a = fmaf(f.x,Ue[4*q+0],a); a = fmaf(f.y,Ue[4*q+1],a);
            a = fmaf(f.z,Ue[4*q+2],a); a = fmaf(f.w,Ue[4*q+3],a);
        }
        atomicAdd(&out[nodes[r/3]*3 + (r%3)], a);
    }
}

extern "C" void kernel_launch(void* const* d_in, const int* in_sizes, int n_in,
                              void* d_out, int out_size, void* d_ws, size_t ws_size,
                              hipStream_t stream) {
    const float* U       = (const float*)d_in[0];
    const float* rho     = (const float*)d_in[1];
    const float* filters = (const float*)d_in[3];
    float* out = (float*)d_out;

    if (ws_size < WS_NEEDED) {
        hipMemsetAsync(out, 0, (size_t)out_size * sizeof(float), stream);
        fe_apply_atomic<<<dim3(NEL/256), dim3(256), 0, stream>>>(U, rho, filters, out);
        return;
    }

    char* ws = (char*)d_ws;
    float4*        U4     = (float4*)(ws + WS_U4);
    float4*        KUe32  = (float4*)(ws + WS_KUE);
    int*           sorted = (int*)(ws + WS_SORTED);
    unsigned char* types  = (unsigned char*)(ws + WS_TYPES);
    int*           bhist  = (int*)(ws + WS_BHIST);
    int*           bintot = (int*)(ws + WS_BINTOT);

    k1_pack_types_hist<<<dim3(256),        dim3(1024), 0, stream>>>(U, rho, U4, types, bhist);
    k2_scan_init      <<<dim3(256),        dim3(256),  0, stream>>>(bhist, bintot, sorted);
    k3_scatter        <<<dim3(256),        dim3(1024), 0, stream>>>(types, bhist, bintot, sorted);
    k4_apply          <<<dim3(PADMAX/256), dim3(256),  0, stream>>>(U4, filters, sorted, KUe32);
    k5_reduce         <<<dim3(NEL/256),    dim3(256),  0, stream>>>(KUe32, out);
}